// Round 12
// baseline (168.934 us; speedup 1.0000x reference)
//
#include <hip/hip_runtime.h>

#define BB   8
#define CC   64
#define HWN  19200
#define NPTS 12800
#define NSUB 3200
#define KNN  16
#define OUTN (HWN + NSUB)   // 22400

typedef __attribute__((ext_vector_type(8))) short short8;
typedef __attribute__((ext_vector_type(4))) float floatx4;

__device__ __forceinline__ unsigned short f2bf(float f) {
    union { float f; unsigned int i; } v; v.f = f;
    unsigned int r = v.i + 0x7fffu + ((v.i >> 16) & 1u);
    return (unsigned short)(r >> 16);
}
__device__ __forceinline__ float bf2f(unsigned short u) {
    union { unsigned int i; float f; } v; v.i = ((unsigned int)u) << 16; return v.f;
}

struct P {
    const float* pfeat; const float* rgb;
    const float* w0; const float* w1; const float* w2; const float* w3;
    const float* s_pp; const float* b_pp;
    const float* s_rp; const float* b_rp;
    const float* s_pf; const float* b_pf;
    const float* s_rf; const float* b_rf;
    const int* pool_idx; const int* p2r_idx; const int* r2p_idx;
    ushort* wB; ushort* pfT; ushort* rgbT;
    ushort* pe0T; ushort* p2rT; ushort* r2pT;
    float* out;
};

// ---------------------------------------------------------------------------
// K1 (frozen, R8): transpose f32 [B][C][N] -> bf16 [B][N][C], 128 n/block,
// float4 loads, ushort8 stores. grid 2096. ~at 98MB BW floor.
// ---------------------------------------------------------------------------
__global__ __launch_bounds__(256) void k_p1(P p) {
    __shared__ ushort sm[2][64 * 65];
    int w = blockIdx.x, tid = threadIdx.x;
    if (w >= 2000) {
        int i = (w - 2000) * 256 + tid;
        float v;
        if (i < 4096)       v = p.w0[i];
        else if (i < 8192)  v = p.w1[i - 4096];
        else if (i < 16384) v = p.w2[i - 8192];
        else                v = p.w3[i - 16384];
        p.wB[i] = f2bf(v);
        return;
    }
    bool isR = (w >= 800);
    int v0 = isR ? w - 800 : w;
    int b = v0 & 7, xx = v0 >> 3;
    const float* src = (isR ? p.rgb : p.pfeat);
    ushort* outp     = (isR ? p.rgbT : p.pfT);
    int N  = isR ? HWN : NPTS;
    int n0 = xx * 128;
    src += (size_t)b * CC * N + n0;

    int l = tid & 15, ch = tid >> 4;
    float4 v[2][4];
    #pragma unroll
    for (int s = 0; s < 2; ++s)
        #pragma unroll
        for (int it = 0; it < 4; ++it)
            v[s][it] = *(const float4*)(src + (size_t)(ch + 16 * it) * N + s * 64 + 4 * l);
    #pragma unroll
    for (int s = 0; s < 2; ++s)
        #pragma unroll
        for (int it = 0; it < 4; ++it) {
            int c = ch + 16 * it;
            sm[s][c * 65 + 4 * l + 0] = f2bf(v[s][it].x);
            sm[s][c * 65 + 4 * l + 1] = f2bf(v[s][it].y);
            sm[s][c * 65 + 4 * l + 2] = f2bf(v[s][it].z);
            sm[s][c * 65 + 4 * l + 3] = f2bf(v[s][it].w);
        }
    __syncthreads();
    ushort* dst = outp + ((size_t)b * N + n0) * CC;
    int c8 = (tid & 7) * 8;
    #pragma unroll
    for (int pass = 0; pass < 4; ++pass) {
        int n_loc = (tid >> 3) + 32 * pass;
        int s = n_loc >> 6, n = n_loc & 63;
        short8 r;
        #pragma unroll
        for (int u = 0; u < 8; ++u)
            r[u] = (short)sm[s][(c8 + u) * 65 + n];
        *(short8*)(dst + (size_t)n_loc * CC + c8) = r;
    }
}

// ---------------------------------------------------------------------------
// K2 (frozen, R8): gather + maxpool + pre-conv GEMM. grid 800.
// ---------------------------------------------------------------------------
__global__ __launch_bounds__(256) void k_p2(P p) {
    __shared__ ushort sm[64 * 72];
    int w = blockIdx.x, tid = threadIdx.x;
    bool pt = (w < 400);
    int v0 = pt ? w : w - 400;
    int b = v0 & 7, xx = v0 >> 3;
    int m0 = xx * 64;
    const ushort* xT  = pt ? p.pfT : p.rgbT;
    const int*    idx = pt ? p.pool_idx : p.r2p_idx;
    int Nin           = pt ? NPTS : HWN;
    const ushort* W   = pt ? p.wB : p.wB + 4096;   // [64][64]
    const float*  sv  = pt ? p.s_pp : p.s_rp;
    const float*  bv  = pt ? p.b_pp : p.b_rp;
    ushort*       dst = pt ? p.p2rT : p.r2pT;

    int c8   = (tid & 7) * 8;
    int mloc = tid >> 3;          // 0..31: 32 points per pass
    const ushort* xb = xT + (size_t)b * Nin * CC + c8;
    #pragma unroll
    for (int pass = 0; pass < 2; ++pass) {
        int ml = mloc + pass * 32;
        int m  = m0 + ml;
        const int4* ip4 = (const int4*)(idx + ((size_t)b * NSUB + m) * KNN);
        int4 q0 = ip4[0], q1 = ip4[1], q2 = ip4[2], q3 = ip4[3];
        int js[16] = { q0.x, q0.y, q0.z, q0.w, q1.x, q1.y, q1.z, q1.w,
                       q2.x, q2.y, q2.z, q2.w, q3.x, q3.y, q3.z, q3.w };
        float a[8];
        #pragma unroll
        for (int u = 0; u < 8; ++u) a[u] = -1e30f;
        #pragma unroll
        for (int k = 0; k < KNN; ++k) {
            short8 val = *(const short8*)(xb + (size_t)js[k] * CC);
            #pragma unroll
            for (int u = 0; u < 8; ++u)
                a[u] = fmaxf(a[u], bf2f((unsigned short)val[u]));
        }
        short8 r;
        #pragma unroll
        for (int u = 0; u < 8; ++u) r[u] = (short)f2bf(a[u]);
        *(short8*)(&sm[ml * 72 + c8]) = r;
        if (pt)
            *(short8*)(p.pe0T + ((size_t)b * NSUB + m) * CC + c8) = r;
    }
    __syncthreads();
    int wave = tid >> 6, lane = tid & 63;
    int l15 = lane & 15, quad = lane >> 4;
    int nloc0 = wave * 16;
    floatx4 acc[4] = {{0.f,0.f,0.f,0.f},{0.f,0.f,0.f,0.f},{0.f,0.f,0.f,0.f},{0.f,0.f,0.f,0.f}};
    #pragma unroll
    for (int kk = 0; kk < 2; ++kk) {
        short8 a = *(const short8*)(&sm[(nloc0 + l15) * 72 + kk * 32 + quad * 8]);
        #pragma unroll
        for (int t = 0; t < 4; ++t) {
            short8 wf = *(const short8*)(W + (size_t)(t * 16 + l15) * CC + kk * 32 + quad * 8);
            acc[t] = __builtin_amdgcn_mfma_f32_16x16x32_bf16(a, wf, acc[t], 0, 0, 0);
        }
    }
    #pragma unroll
    for (int t = 0; t < 4; ++t) {
        int o = t * 16 + l15;
        float ss = sv[o], bb2 = bv[o];
        #pragma unroll
        for (int r = 0; r < 4; ++r) {
            int n = m0 + nloc0 + quad * 4 + r;
            float y = fmaxf(acc[t][r] * ss + bb2, 0.f);
            dst[((size_t)b * NSUB + n) * CC + o] = f2bf(y);
        }
    }
}

// ---------------------------------------------------------------------------
// K3 (finer grain): both fuse GEMMs -> d_out. D = W(A rows=o)*X(B cols=n),
// K=128. 128-thread blocks (2 waves x 64 cols = 128 cols/block) -> grid 1400
// (rgb 150x8, pt 25x8): 5.5 blocks/CU (vs 2.75) halves the tail quantum and
// overlaps one block's store drain with ~5 others' compute. Both paths divide
// evenly -> no activity guard. Per-wave structure identical to R11 (preloaded
// B-fragments, per-o-tile MFMA + immediate nontemporal stores).
// ---------------------------------------------------------------------------
__global__ __launch_bounds__(128) void k_p3(P p) {
    int w = blockIdx.x, tid = threadIdx.x;
    bool rp = (w < 1200);
    int v0 = rp ? w : w - 1200;
    int b = v0 & 7, x0 = v0 >> 3;     // rgb 0..149 / pt 0..24
    const ushort* x1T = rp ? p.rgbT : p.pe0T;
    const ushort* x2T = rp ? p.p2rT : p.r2pT;
    int N             = rp ? HWN : NSUB;
    int pos0          = rp ? 0 : HWN;
    const ushort* W   = rp ? p.wB + 8192 : p.wB + 16384;   // [64][128]
    const float*  sv  = rp ? p.s_pf : p.s_rf;
    const float*  bv  = rp ? p.b_pf : p.b_rf;

    int wave = tid >> 6, lane = tid & 63;   // wave 0..1
    int l15 = lane & 15, quad = lane >> 4;
    int nc = x0 * 128 + wave * 64 + l15 * 4;   // lane's 4 consecutive cols

    // preload all B-fragments: xf[kk][g], 16 independent 16B loads
    short8 xf[4][4];
    {
        const ushort* r1[4];
        const ushort* r2[4];
        if (rp) {
            int4 i4 = *(const int4*)(p.p2r_idx + (size_t)b * N + nc);
            int n2s[4] = { i4.x, i4.y, i4.z, i4.w };
            #pragma unroll
            for (int g = 0; g < 4; ++g) {
                r1[g] = x1T + ((size_t)b * N + nc + g) * CC + quad * 8;
                r2[g] = x2T + ((size_t)b * NSUB + n2s[g]) * CC + quad * 8;
            }
        } else {
            #pragma unroll
            for (int g = 0; g < 4; ++g) {
                r1[g] = x1T + ((size_t)b * N + nc + g) * CC + quad * 8;
                r2[g] = x2T + ((size_t)b * NSUB + nc + g) * CC + quad * 8;
            }
        }
        #pragma unroll
        for (int g = 0; g < 4; ++g) {
            xf[0][g] = *(const short8*)(r1[g]);
            xf[1][g] = *(const short8*)(r1[g] + 32);
            xf[2][g] = *(const short8*)(r2[g]);
            xf[3][g] = *(const short8*)(r2[g] + 32);
        }
    }

    float* outb = p.out + (size_t)b * CC * OUTN + pos0 + nc;
    #pragma unroll
    for (int t = 0; t < 4; ++t) {
        floatx4 acc[4] = {{0.f,0.f,0.f,0.f},{0.f,0.f,0.f,0.f},
                          {0.f,0.f,0.f,0.f},{0.f,0.f,0.f,0.f}};
        #pragma unroll
        for (int kk = 0; kk < 4; ++kk) {
            short8 wf = *(const short8*)(W + (size_t)(t * 16 + l15) * 128 + kk * 32 + quad * 8);
            #pragma unroll
            for (int g = 0; g < 4; ++g)
                acc[g] = __builtin_amdgcn_mfma_f32_16x16x32_bf16(wf, xf[kk][g], acc[g], 0, 0, 0);
        }
        #pragma unroll
        for (int r = 0; r < 4; ++r) {
            int o = t * 16 + quad * 4 + r;
            float ss = sv[o], bb2 = bv[o];
            floatx4 y;
            y[0] = fmaxf(acc[0][r] * ss + bb2, 0.f);
            y[1] = fmaxf(acc[1][r] * ss + bb2, 0.f);
            y[2] = fmaxf(acc[2][r] * ss + bb2, 0.f);
            y[3] = fmaxf(acc[3][r] * ss + bb2, 0.f);
            __builtin_nontemporal_store(y, (floatx4*)(outb + (size_t)o * OUTN));
        }
    }
}

extern "C" void kernel_launch(void* const* d_in, const int* in_sizes, int n_in,
                              void* d_out, int out_size, void* d_ws, size_t ws_size,
                              hipStream_t stream) {
    char* ws = (char*)d_ws;
    ushort* wB   = (ushort*)ws; ws += 24576 * 2;
    ushort* pfT  = (ushort*)ws; ws += (size_t)BB * NPTS * CC * 2;
    ushort* rgbT = (ushort*)ws; ws += (size_t)BB * HWN  * CC * 2;
    ushort* pe0T = (ushort*)ws; ws += (size_t)BB * NSUB * CC * 2;
    ushort* p2rT = (ushort*)ws; ws += (size_t)BB * NSUB * CC * 2;
    ushort* r2pT = (ushort*)ws; ws += (size_t)BB * NSUB * CC * 2;

    P p;
    p.pfeat = (const float*)d_in[1];
    p.rgb   = (const float*)d_in[0];
    p.w0    = (const float*)d_in[2];
    p.w1    = (const float*)d_in[8];
    p.w2    = (const float*)d_in[5];
    p.w3    = (const float*)d_in[11];
    p.s_pp  = (const float*)d_in[3];   p.b_pp = (const float*)d_in[4];
    p.s_rp  = (const float*)d_in[9];   p.b_rp = (const float*)d_in[10];
    p.s_pf  = (const float*)d_in[6];   p.b_pf = (const float*)d_in[7];
    p.s_rf  = (const float*)d_in[12];  p.b_rf = (const float*)d_in[13];
    p.pool_idx = (const int*)d_in[14];
    p.p2r_idx  = (const int*)d_in[15];
    p.r2p_idx  = (const int*)d_in[16];
    p.wB = wB; p.pfT = pfT; p.rgbT = rgbT;
    p.pe0T = pe0T; p.p2rT = p2rT; p.r2pT = r2pT;
    p.out = (float*)d_out;

    k_p1<<<dim3(2096), 256, 0, stream>>>(p);
    k_p2<<<dim3(800),  256, 0, stream>>>(p);
    k_p3<<<dim3(1400), 128, 0, stream>>>(p);
}